// Round 4
// baseline (16203.386 us; speedup 1.0000x reference)
//
#include <hip/hip_runtime.h>
#include <math.h>

typedef __attribute__((ext_vector_type(4))) float f32x4;

#define WS_HPROJ 0
#define WS_CT    16777216

__device__ __forceinline__ float gelu_f(float x) {
    return 0.5f * x * (1.0f + erff(0.70710678118654752440f * x));
}

__device__ __forceinline__ void exp_se3_dev(const float xi[6], float R[9], float t[3]) {
    float wx = xi[0], wy = xi[1], wz = xi[2];
    float vx = xi[3], vy = xi[4], vz = xi[5];
    float ww = wx*wx + wy*wy + wz*wz;
    float th2 = ww + 1e-20f;
    float th = sqrtf(th2);
    float A, Bc, Cc;
    if (th < 1e-3f) {
        A = 1.f - th2*(1.f/6.f);
        Bc = 0.5f - th2*(1.f/24.f);
        Cc = (1.f/6.f) - th2*(1.f/120.f);
    } else {
        float s = sinf(th), c = cosf(th);
        A = s/th;
        Bc = (1.f - c)/th2;
        Cc = (th - s)/(th2*th);
    }
    float W2[9] = { wx*wx - ww, wx*wy,       wx*wz,
                    wy*wx,      wy*wy - ww,  wy*wz,
                    wz*wx,      wz*wy,       wz*wz - ww };
    R[0] = 1.f + Bc*W2[0];  R[1] = -A*wz + Bc*W2[1]; R[2] =  A*wy + Bc*W2[2];
    R[3] =  A*wz + Bc*W2[3]; R[4] = 1.f + Bc*W2[4];  R[5] = -A*wx + Bc*W2[5];
    R[6] = -A*wy + Bc*W2[6]; R[7] =  A*wx + Bc*W2[7]; R[8] = 1.f + Bc*W2[8];
    float V[9];
    V[0] = 1.f + Cc*W2[0];   V[1] = -Bc*wz + Cc*W2[1]; V[2] =  Bc*wy + Cc*W2[2];
    V[3] =  Bc*wz + Cc*W2[3]; V[4] = 1.f + Cc*W2[4];   V[5] = -Bc*wx + Cc*W2[5];
    V[6] = -Bc*wy + Cc*W2[6]; V[7] =  Bc*wx + Cc*W2[7]; V[8] = 1.f + Cc*W2[8];
    t[0] = V[0]*vx + V[1]*vy + V[2]*vz;
    t[1] = V[3]*vx + V[4]*vy + V[5]*vz;
    t[2] = V[6]*vx + V[7]*vy + V[8]*vz;
}

__device__ __forceinline__ void log_se3_dev(const float R[9], const float p[3], float xi[6]) {
    float tr = R[0] + R[4] + R[8];
    float c = 0.5f*(tr - 1.f);
    c = fminf(fmaxf(c, -1.f + 1e-7f), 1.f - 1e-7f);
    float th = acosf(c);
    float fac, D;
    if (th < 1e-3f) {
        fac = 0.5f + th*th*(1.f/12.f);
        D = 1.f/12.f;
    } else {
        float s = sinf(th), co = cosf(th);
        fac = th/(2.f*s);
        D = (1.f - th*s/(2.f*(1.f - co)))/(th*th);
    }
    float wx = fac*(R[7] - R[5]);
    float wy = fac*(R[2] - R[6]);
    float wz = fac*(R[3] - R[1]);
    float ww = wx*wx + wy*wy + wz*wz;
    float W2[9] = { wx*wx - ww, wx*wy,       wx*wz,
                    wy*wx,      wy*wy - ww,  wy*wz,
                    wz*wx,      wz*wy,       wz*wz - ww };
    float Vi[9];
    Vi[0] = 1.f + D*W2[0];    Vi[1] =  0.5f*wz + D*W2[1]; Vi[2] = -0.5f*wy + D*W2[2];
    Vi[3] = -0.5f*wz + D*W2[3]; Vi[4] = 1.f + D*W2[4];    Vi[5] =  0.5f*wx + D*W2[5];
    Vi[6] =  0.5f*wy + D*W2[6]; Vi[7] = -0.5f*wx + D*W2[7]; Vi[8] = 1.f + D*W2[8];
    xi[0] = wx; xi[1] = wy; xi[2] = wz;
    xi[3] = Vi[0]*p[0] + Vi[1]*p[1] + Vi[2]*p[2];
    xi[4] = Vi[3]*p[0] + Vi[4]*p[1] + Vi[5]*p[2];
    xi[5] = Vi[6]*p[0] + Vi[7]*p[1] + Vi[8]*p[2];
}

// ct[s][col] = b0[col] + temb(s/ns) @ W0[4102:4166]
__global__ void prep_ct(const float* __restrict__ W0, const float* __restrict__ b0,
                        const int* __restrict__ nsp, float* __restrict__ ct) {
    int s = blockIdx.x;
    int ns = *nsp;
    if (s >= ns) return;
    int col = threadIdx.x;
    float t = (float)s / (float)ns;
    float acc = b0[col];
    #pragma unroll
    for (int d = 0; d < 32; d++) {
        float f = expf((float)d * -0.29710775393471563f);  // -ln(10000)/31
        float e = t * f;
        acc += sinf(e) * W0[(size_t)(4102 + d)*256 + col];
        acc += cosf(e) * W0[(size_t)(4134 + d)*256 + col];
    }
    ct[s*256 + col] = acc;
}

// ---------------------------------------------------------------------------
// k2v: pure-VALU fp32  hproj = h @ W0[:4096]  +  fused gripper head
// grid 512 x 256; 32 rows per block.
// ---------------------------------------------------------------------------
__launch_bounds__(256)
__global__ void k2v(const float* __restrict__ h, const float* __restrict__ W0,
                    const float* __restrict__ gW1, const float* __restrict__ gb1,
                    const float* __restrict__ gW2, const float* __restrict__ gb2,
                    float* __restrict__ hproj, float* __restrict__ grip) {
    __shared__ float hs[256*36];     // [k][row] transposed stage, pad 36
    __shared__ float gpart[32*16];

    const int tid = threadIdx.x;
    const int r0 = blockIdx.x * 32;
    const int cg = tid & 63;         // main: col group cg*4
    const int rg = tid >> 6;         // main: rows rg*8..+7
    const int gc = tid & 15;         // grip: col group gc*4
    const int grp = tid >> 4;        // grip: rows grp*2..+1

    f32x4 acc[8];
    f32x4 gacc[2];
    const f32x4 zv = {0.f, 0.f, 0.f, 0.f};
    #pragma unroll
    for (int r = 0; r < 8; r++) acc[r] = zv;
    gacc[0] = zv; gacc[1] = zv;

    for (int ch = 0; ch < 16; ch++) {
        const int k0 = ch * 256;
        __syncthreads();
        #pragma unroll
        for (int j = 0; j < 8; j++) {
            int f = tid + j*256;
            int row = f >> 6, c4 = (f & 63) * 4;
            f32x4 v = *(const f32x4*)(h + (size_t)(r0 + row)*4096 + k0 + c4);
            hs[(c4+0)*36 + row] = v[0];
            hs[(c4+1)*36 + row] = v[1];
            hs[(c4+2)*36 + row] = v[2];
            hs[(c4+3)*36 + row] = v[3];
        }
        __syncthreads();
        for (int k = 0; k < 256; k++) {
            f32x4 wv = *(const f32x4*)(W0 + (size_t)(k0 + k)*256 + cg*4);
            f32x4 h0 = *(const f32x4*)(hs + k*36 + rg*8);
            f32x4 h1 = *(const f32x4*)(hs + k*36 + rg*8 + 4);
            acc[0] += h0[0]*wv; acc[1] += h0[1]*wv;
            acc[2] += h0[2]*wv; acc[3] += h0[3]*wv;
            acc[4] += h1[0]*wv; acc[5] += h1[1]*wv;
            acc[6] += h1[2]*wv; acc[7] += h1[3]*wv;
        }
        for (int k = 0; k < 256; k++) {
            f32x4 wg = *(const f32x4*)(gW1 + (size_t)(k0 + k)*64 + gc*4);
            float a0 = hs[k*36 + grp*2 + 0];
            float a1 = hs[k*36 + grp*2 + 1];
            gacc[0] += a0*wg;
            gacc[1] += a1*wg;
        }
    }
    // hproj epilogue
    #pragma unroll
    for (int r = 0; r < 8; r++)
        *(f32x4*)(hproj + (size_t)(r0 + rg*8 + r)*256 + cg*4) = acc[r];
    // gripper epilogue
    #pragma unroll
    for (int rr = 0; rr < 2; rr++) {
        int row = grp*2 + rr;
        float s = 0.f;
        #pragma unroll
        for (int c = 0; c < 4; c++)
            s += gelu_f(gacc[rr][c] + gb1[gc*4 + c]) * gW2[gc*4 + c];
        gpart[row*16 + gc] = s;
    }
    __syncthreads();
    if (tid < 32) {
        float g = gb2[0];
        #pragma unroll
        for (int i = 0; i < 16; i++) g += gpart[tid*16 + i];
        grip[r0 + tid] = 1.f / (1.f + expf(-g));
    }
}

// ---------------------------------------------------------------------------
// k3v: pure-VALU fp32 persistent 10-step MLP + SE3 integrator.
// grid 512 x 256; 32 rows per block; thread = (prow = tid>>3, oct = tid&7).
// ---------------------------------------------------------------------------
__launch_bounds__(256)
__global__ void k3v(const float* __restrict__ hproj,
                    const float* __restrict__ Wr,
                    const float* __restrict__ ct,
                    const float* __restrict__ W0,
                    const float* __restrict__ Wout,
                    const float* __restrict__ bout,
                    const float* __restrict__ br,
                    const float* __restrict__ gr,
                    const float* __restrict__ ber,
                    const float* __restrict__ g0,
                    const float* __restrict__ be0,
                    const float* __restrict__ xi0,
                    const int* __restrict__ nsp,
                    float* __restrict__ out) {
    __shared__ float Yf[32*260];
    __shared__ float w0xiL[6*256];
    __shared__ float ctL[256];
    __shared__ float Xsh[32][12];
    __shared__ float xiL[32*6];
    __shared__ float rowred[32*16];
    __shared__ float vpart[32*8*6];

    const int tid = threadIdx.x;
    const int r0 = blockIdx.x * 32;
    const int prow = tid >> 3;
    const int oct = tid & 7;
    const int cb = oct * 32;
    const int ns = *nsp;
    const float dt = 1.0f / (float)ns;

    if (tid < 32) {
        float xi[6];
        #pragma unroll
        for (int j = 0; j < 6; j++) xi[j] = 0.1f * xi0[(size_t)(r0 + tid)*6 + j];
        float R[9], tt[3];
        exp_se3_dev(xi, R, tt);
        #pragma unroll
        for (int j = 0; j < 9; j++) Xsh[tid][j] = R[j];
        #pragma unroll
        for (int j = 0; j < 3; j++) Xsh[tid][9+j] = tt[j];
    }
    for (int i = tid; i < 1536; i += 256)
        w0xiL[i] = W0[(size_t)4096*256 + i];
    __syncthreads();

    for (int s = 0; s < ns; s++) {
        ctL[tid] = ct[s*256 + tid];
        if (tid < 32) {
            float R[9], p[3], xi[6];
            #pragma unroll
            for (int j = 0; j < 9; j++) R[j] = Xsh[tid][j];
            #pragma unroll
            for (int j = 0; j < 3; j++) p[j] = Xsh[tid][9+j];
            log_se3_dev(R, p, xi);
            #pragma unroll
            for (int j = 0; j < 6; j++) xiL[tid*6 + j] = xi[j];
        }
        __syncthreads();

        // ---------------- layer 0 ----------------
        float gv[32];
        {
            float xr[6];
            #pragma unroll
            for (int j = 0; j < 6; j++) xr[j] = xiL[prow*6 + j];
            const float* hp = hproj + (size_t)(r0 + prow)*256 + cb;
            #pragma unroll
            for (int c4 = 0; c4 < 8; c4++) {
                f32x4 hv = *(const f32x4*)(hp + c4*4);
                f32x4 cv = *(const f32x4*)(ctL + cb + c4*4);
                f32x4 pr = hv + cv;
                #pragma unroll
                for (int j = 0; j < 6; j++)
                    pr += xr[j] * *(const f32x4*)(w0xiL + j*256 + cb + c4*4);
                #pragma unroll
                for (int e = 0; e < 4; e++) gv[c4*4 + e] = gelu_f(pr[e]);
            }
            float ps = 0.f, pq = 0.f;
            #pragma unroll
            for (int c = 0; c < 32; c++) { ps += gv[c]; pq += gv[c]*gv[c]; }
            rowred[prow*16 + oct*2 + 0] = ps;
            rowred[prow*16 + oct*2 + 1] = pq;
        }
        __syncthreads();
        if (tid < 32) {
            float sm = 0.f, sq = 0.f;
            #pragma unroll
            for (int o = 0; o < 8; o++) { sm += rowred[tid*16 + o*2]; sq += rowred[tid*16 + o*2 + 1]; }
            float mean = sm * (1.f/256.f);
            float var  = sq * (1.f/256.f) - mean*mean;
            rowred[tid*16 + 0] = mean;
            rowred[tid*16 + 1] = rsqrtf(var + 1e-5f);
        }
        __syncthreads();
        {
            float mean = rowred[prow*16 + 0], rstd = rowred[prow*16 + 1];
            #pragma unroll
            for (int c = 0; c < 32; c++)
                Yf[prow*260 + cb + c] = (gv[c] - mean)*rstd*g0[cb + c] + be0[cb + c];
        }

        // ---------------- layers 1..3 ----------------
        #pragma unroll 1
        for (int L = 0; L < 3; L++) {
            __syncthreads();   // Yf writes visible before reads
            const float* WL = Wr + (size_t)L*65536;
            f32x4 acc4[8];
            const f32x4 zv = {0.f, 0.f, 0.f, 0.f};
            #pragma unroll
            for (int i = 0; i < 8; i++) acc4[i] = zv;
            for (int k = 0; k < 256; k++) {
                float yv = Yf[prow*260 + k];
                const float* wk = WL + (size_t)k*256 + cb;
                #pragma unroll
                for (int i = 0; i < 8; i++) {
                    f32x4 wv = *(const f32x4*)(wk + i*4);
                    acc4[i] += yv * wv;
                }
            }
            float u[32];
            float ps = 0.f, pq = 0.f;
            #pragma unroll
            for (int i = 0; i < 8; i++)
                #pragma unroll
                for (int e = 0; e < 4; e++) {
                    float x = gelu_f(acc4[i][e] + br[L*256 + cb + i*4 + e]);
                    u[i*4 + e] = x;
                    ps += x; pq += x*x;
                }
            rowred[prow*16 + oct*2 + 0] = ps;
            rowred[prow*16 + oct*2 + 1] = pq;
            __syncthreads();
            if (tid < 32) {
                float sm = 0.f, sq = 0.f;
                #pragma unroll
                for (int o = 0; o < 8; o++) { sm += rowred[tid*16 + o*2]; sq += rowred[tid*16 + o*2 + 1]; }
                float mean = sm * (1.f/256.f);
                float var  = sq * (1.f/256.f) - mean*mean;
                rowred[tid*16 + 0] = mean;
                rowred[tid*16 + 1] = rsqrtf(var + 1e-5f);
            }
            __syncthreads();
            {
                float mean = rowred[prow*16 + 0], rstd = rowred[prow*16 + 1];
                #pragma unroll
                for (int c = 0; c < 32; c++)
                    Yf[prow*260 + cb + c] = (u[c] - mean)*rstd*gr[L*256 + cb + c] + ber[L*256 + cb + c];
            }
        }
        __syncthreads();

        // ---------------- v = Y @ Wout ----------------
        {
            float p6[6] = {0.f, 0.f, 0.f, 0.f, 0.f, 0.f};
            #pragma unroll
            for (int k = 0; k < 32; k++) {
                float yv = Yf[prow*260 + cb + k];
                #pragma unroll
                for (int j = 0; j < 6; j++)
                    p6[j] += yv * Wout[(size_t)(cb + k)*6 + j];
            }
            #pragma unroll
            for (int j = 0; j < 6; j++) vpart[(prow*8 + oct)*6 + j] = p6[j];
        }
        __syncthreads();
        if (tid < 32) {
            float v6[6];
            #pragma unroll
            for (int j = 0; j < 6; j++) {
                float sv = 0.f;
                #pragma unroll
                for (int o = 0; o < 8; o++) sv += vpart[(tid*8 + o)*6 + j];
                v6[j] = dt * (sv + bout[j]);
            }
            float Re[9], te[3];
            exp_se3_dev(v6, Re, te);
            float R0[9], t0[3];
            #pragma unroll
            for (int j = 0; j < 9; j++) R0[j] = Xsh[tid][j];
            #pragma unroll
            for (int j = 0; j < 3; j++) t0[j] = Xsh[tid][9+j];
            float Rn[9], tn[3];
            #pragma unroll
            for (int i = 0; i < 3; i++)
                #pragma unroll
                for (int j2 = 0; j2 < 3; j2++)
                    Rn[i*3+j2] = R0[i*3+0]*Re[0*3+j2] + R0[i*3+1]*Re[1*3+j2] + R0[i*3+2]*Re[2*3+j2];
            #pragma unroll
            for (int i = 0; i < 3; i++)
                tn[i] = R0[i*3+0]*te[0] + R0[i*3+1]*te[1] + R0[i*3+2]*te[2] + t0[i];
            #pragma unroll
            for (int j = 0; j < 9; j++) Xsh[tid][j] = Rn[j];
            #pragma unroll
            for (int j = 0; j < 3; j++) Xsh[tid][9+j] = tn[j];
            if (s == ns - 1) {
                float* o = out + (size_t)(r0 + tid)*16;
                o[0]  = Rn[0]; o[1]  = Rn[1]; o[2]  = Rn[2]; o[3]  = tn[0];
                o[4]  = Rn[3]; o[5]  = Rn[4]; o[6]  = Rn[5]; o[7]  = tn[1];
                o[8]  = Rn[6]; o[9]  = Rn[7]; o[10] = Rn[8]; o[11] = tn[2];
                o[12] = 0.f; o[13] = 0.f; o[14] = 0.f; o[15] = 1.f;
            }
        }
        __syncthreads();
    }
}

extern "C" void kernel_launch(void* const* d_in, const int* in_sizes, int n_in,
                              void* d_out, int out_size, void* d_ws, size_t ws_size,
                              hipStream_t stream) {
    const float* h    = (const float*)d_in[0];
    const float* xi0  = (const float*)d_in[1];
    const float* W0   = (const float*)d_in[2];
    const float* b0   = (const float*)d_in[3];
    const float* g0   = (const float*)d_in[4];
    const float* be0  = (const float*)d_in[5];
    const float* Wr   = (const float*)d_in[6];
    const float* br   = (const float*)d_in[7];
    const float* gr   = (const float*)d_in[8];
    const float* ber  = (const float*)d_in[9];
    const float* Wout = (const float*)d_in[10];
    const float* bout = (const float*)d_in[11];
    const float* gW1  = (const float*)d_in[12];
    const float* gb1  = (const float*)d_in[13];
    const float* gW2  = (const float*)d_in[14];
    const float* gb2  = (const float*)d_in[15];
    const int*   nsp  = (const int*)d_in[16];
    float* out = (float*)d_out;

    char* ws = (char*)d_ws;
    float* hproj = (float*)(ws + WS_HPROJ);
    float* ct    = (float*)(ws + WS_CT);

    prep_ct<<<16, 256, 0, stream>>>(W0, b0, nsp, ct);
    k2v<<<512, 256, 0, stream>>>(h, W0, gW1, gb1, gW2, gb2, hproj, out + (size_t)16384*16);
    k3v<<<512, 256, 0, stream>>>(hproj, Wr, ct, W0, Wout, bout, br, gr, ber, g0, be0, xi0, nsp, out);
}

// Round 5
// 1191.083 us; speedup vs baseline: 13.6039x; 13.6039x over previous
//
#include <hip/hip_runtime.h>
#include <math.h>

typedef __attribute__((ext_vector_type(8))) __bf16 bf16_8;
typedef __attribute__((ext_vector_type(4))) float f32x4;

#define WS_HPROJ 0
#define WS_BT    16777216
#define WS_WRT   19398656
#define WS_CT    19791872

__device__ __forceinline__ float gelu_f(float x) {
    return 0.5f * x * (1.0f + erff(0.70710678118654752440f * x));
}

__device__ __forceinline__ void exp_se3_dev(const float xi[6], float R[9], float t[3]) {
    float wx = xi[0], wy = xi[1], wz = xi[2];
    float vx = xi[3], vy = xi[4], vz = xi[5];
    float ww = wx*wx + wy*wy + wz*wz;
    float th2 = ww + 1e-20f;
    float th = sqrtf(th2);
    float A, Bc, Cc;
    if (th < 1e-3f) {
        A = 1.f - th2*(1.f/6.f);
        Bc = 0.5f - th2*(1.f/24.f);
        Cc = (1.f/6.f) - th2*(1.f/120.f);
    } else {
        float s = sinf(th), c = cosf(th);
        A = s/th;
        Bc = (1.f - c)/th2;
        Cc = (th - s)/(th2*th);
    }
    float W2[9] = { wx*wx - ww, wx*wy,       wx*wz,
                    wy*wx,      wy*wy - ww,  wy*wz,
                    wz*wx,      wz*wy,       wz*wz - ww };
    R[0] = 1.f + Bc*W2[0];  R[1] = -A*wz + Bc*W2[1]; R[2] =  A*wy + Bc*W2[2];
    R[3] =  A*wz + Bc*W2[3]; R[4] = 1.f + Bc*W2[4];  R[5] = -A*wx + Bc*W2[5];
    R[6] = -A*wy + Bc*W2[6]; R[7] =  A*wx + Bc*W2[7]; R[8] = 1.f + Bc*W2[8];
    float V[9];
    V[0] = 1.f + Cc*W2[0];   V[1] = -Bc*wz + Cc*W2[1]; V[2] =  Bc*wy + Cc*W2[2];
    V[3] =  Bc*wz + Cc*W2[3]; V[4] = 1.f + Cc*W2[4];   V[5] = -Bc*wx + Cc*W2[5];
    V[6] = -Bc*wy + Cc*W2[6]; V[7] =  Bc*wx + Cc*W2[7]; V[8] = 1.f + Cc*W2[8];
    t[0] = V[0]*vx + V[1]*vy + V[2]*vz;
    t[1] = V[3]*vx + V[4]*vy + V[5]*vz;
    t[2] = V[6]*vx + V[7]*vy + V[8]*vz;
}

__device__ __forceinline__ void log_se3_dev(const float R[9], const float p[3], float xi[6]) {
    float tr = R[0] + R[4] + R[8];
    float c = 0.5f*(tr - 1.f);
    c = fminf(fmaxf(c, -1.f + 1e-7f), 1.f - 1e-7f);
    float th = acosf(c);
    float fac, D;
    if (th < 1e-3f) {
        fac = 0.5f + th*th*(1.f/12.f);
        D = 1.f/12.f;
    } else {
        float s = sinf(th), co = cosf(th);
        fac = th/(2.f*s);
        D = (1.f - th*s/(2.f*(1.f - co)))/(th*th);
    }
    float wx = fac*(R[7] - R[5]);
    float wy = fac*(R[2] - R[6]);
    float wz = fac*(R[3] - R[1]);
    float ww = wx*wx + wy*wy + wz*wz;
    float W2[9] = { wx*wx - ww, wx*wy,       wx*wz,
                    wy*wx,      wy*wy - ww,  wy*wz,
                    wz*wx,      wz*wy,       wz*wz - ww };
    float Vi[9];
    Vi[0] = 1.f + D*W2[0];    Vi[1] =  0.5f*wz + D*W2[1]; Vi[2] = -0.5f*wy + D*W2[2];
    Vi[3] = -0.5f*wz + D*W2[3]; Vi[4] = 1.f + D*W2[4];    Vi[5] =  0.5f*wx + D*W2[5];
    Vi[6] =  0.5f*wy + D*W2[6]; Vi[7] = -0.5f*wx + D*W2[7]; Vi[8] = 1.f + D*W2[8];
    xi[0] = wx; xi[1] = wy; xi[2] = wz;
    xi[3] = Vi[0]*p[0] + Vi[1]*p[1] + Vi[2]*p[2];
    xi[4] = Vi[3]*p[0] + Vi[4]*p[1] + Vi[5]*p[2];
    xi[5] = Vi[6]*p[0] + Vi[7]*p[1] + Vi[8]*p[2];
}

// ---------------------------------------------------------------------------
// prep: transpose W0[:4096]|gW1 -> BT[320][4096] bf16, Wr -> WrT[3][256][256] bf16
// ---------------------------------------------------------------------------
__global__ void prep_pack(const float* __restrict__ W0, const float* __restrict__ gW1,
                          const float* __restrict__ Wr, __bf16* __restrict__ BT,
                          __bf16* __restrict__ WrT) {
    __shared__ float t[64][72];
    const int blk = blockIdx.x;
    const int tid = threadIdx.x;
    const float* src; size_t sstride; __bf16* dst; size_t dstride;
    if (blk < 320) {
        int kb = blk & 63, nb = blk >> 6;   // blk = nb*64 + kb, nb<5
        int k0 = kb*64, n0 = nb*64;
        if (nb < 4) { src = W0 + (size_t)k0*256 + n0; sstride = 256; }
        else        { src = gW1 + (size_t)k0*64 + (n0 - 256); sstride = 64; }
        dst = BT + (size_t)n0*4096 + k0; dstride = 4096;
    } else {
        int b = blk - 320;                 // 48 tiles: 3 layers x 4x4
        int L = b >> 4, kb = (b >> 2) & 3, nb = b & 3;
        int k0 = kb*64, n0 = nb*64;
        src = Wr + (size_t)L*65536 + (size_t)k0*256 + n0; sstride = 256;
        dst = WrT + (size_t)L*65536 + (size_t)n0*256 + k0; dstride = 256;
    }
    const int r = tid >> 2, cq = (tid & 3) * 16;
    #pragma unroll
    for (int i = 0; i < 4; i++) {
        float4 v = *(const float4*)(src + (size_t)r*sstride + cq + i*4);
        t[r][cq+i*4+0] = v.x; t[r][cq+i*4+1] = v.y;
        t[r][cq+i*4+2] = v.z; t[r][cq+i*4+3] = v.w;
    }
    __syncthreads();
    bf16_8 o0, o1;
    #pragma unroll
    for (int i = 0; i < 8; i++) { o0[i] = (__bf16)t[cq+i][r]; o1[i] = (__bf16)t[cq+8+i][r]; }
    *(bf16_8*)(dst + (size_t)r*dstride + cq)     = o0;
    *(bf16_8*)(dst + (size_t)r*dstride + cq + 8) = o1;
}

// ct[s][col] = b0[col] + temb(s/ns) @ W0[4102:4166]
__global__ void prep_ct(const float* __restrict__ W0, const float* __restrict__ b0,
                        const int* __restrict__ nsp, float* __restrict__ ct) {
    int s = blockIdx.x;
    int ns = *nsp;
    if (s >= ns) return;
    int col = threadIdx.x;
    float t = (float)s / (float)ns;
    float acc = b0[col];
    #pragma unroll
    for (int d = 0; d < 32; d++) {
        float f = expf((float)d * -0.29710775393471563f);  // -ln(10000)/31
        float e = t * f;
        acc += sinf(e) * W0[(size_t)(4102 + d)*256 + col];
        acc += cosf(e) * W0[(size_t)(4134 + d)*256 + col];
    }
    ct[s*256 + col] = acc;
}

// ---------------------------------------------------------------------------
// k2: h_proj = h @ W0[:4096]  (bf16 MFMA)  +  fused gripper head
// grid 256 x 256 threads; M-tile 64, N = 256 + 64, BK = 64
// ---------------------------------------------------------------------------
__launch_bounds__(256, 1)
__global__ void k2(const float* __restrict__ h, const __bf16* __restrict__ BT,
                   const float* __restrict__ gb1, const float* __restrict__ gW2,
                   const float* __restrict__ gb2, float* __restrict__ hproj,
                   float* __restrict__ grip) {
    __shared__ __align__(16) __bf16 Ash[64*72];
    __shared__ __align__(16) __bf16 Bsh[320*72];
    __shared__ float gpart[64][4];

    const int tid = threadIdx.x;
    const int w = tid >> 6;
    const int l = tid & 63;
    const int q = l >> 4;
    const int ln = l & 15;
    const int m0 = blockIdx.x * 64;

    const int ar = tid >> 2, akq = (tid & 3) * 16;
    const float* hp = h + (size_t)(m0 + ar)*4096 + akq;

    f32x4 acc[4][5];
    const f32x4 zv = {0.f, 0.f, 0.f, 0.f};
    #pragma unroll
    for (int a = 0; a < 4; a++)
        #pragma unroll
        for (int b = 0; b < 5; b++) acc[a][b] = zv;

    float4 pa[4];
    uint4 pb[10];
    #pragma unroll
    for (int c = 0; c < 4; c++) pa[c] = *(const float4*)(hp + c*4);
    #pragma unroll
    for (int j = 0; j < 10; j++) {
        int c = j*256 + tid; int n = c >> 3, pt = c & 7;
        pb[j] = *(const uint4*)(BT + (size_t)n*4096 + pt*8);
    }

    for (int slice = 0; slice < 64; slice++) {
        const int k0 = slice * 64;
        __syncthreads();
        // store A (fp32 -> bf16)
        bf16_8 t0, t1;
        t0[0]=(__bf16)pa[0].x; t0[1]=(__bf16)pa[0].y; t0[2]=(__bf16)pa[0].z; t0[3]=(__bf16)pa[0].w;
        t0[4]=(__bf16)pa[1].x; t0[5]=(__bf16)pa[1].y; t0[6]=(__bf16)pa[1].z; t0[7]=(__bf16)pa[1].w;
        t1[0]=(__bf16)pa[2].x; t1[1]=(__bf16)pa[2].y; t1[2]=(__bf16)pa[2].z; t1[3]=(__bf16)pa[2].w;
        t1[4]=(__bf16)pa[3].x; t1[5]=(__bf16)pa[3].y; t1[6]=(__bf16)pa[3].z; t1[7]=(__bf16)pa[3].w;
        *(bf16_8*)(Ash + ar*72 + akq)     = t0;
        *(bf16_8*)(Ash + ar*72 + akq + 8) = t1;
        // store B
        #pragma unroll
        for (int j = 0; j < 10; j++) {
            int c = j*256 + tid; int n = c >> 3, pt = c & 7;
            *(uint4*)(Bsh + n*72 + pt*8) = pb[j];
        }
        // prefetch next slice
        if (slice < 63) {
            const int kn = k0 + 64;
            #pragma unroll
            for (int c = 0; c < 4; c++) pa[c] = *(const float4*)(hp + kn + c*4);
            #pragma unroll
            for (int j = 0; j < 10; j++) {
                int c = j*256 + tid; int n = c >> 3, pt = c & 7;
                pb[j] = *(const uint4*)(BT + (size_t)n*4096 + kn + pt*8);
            }
        }
        __syncthreads();
        #pragma unroll
        for (int kk = 0; kk < 2; kk++) {
            bf16_8 af[4], bfv[5];
            #pragma unroll
            for (int mt = 0; mt < 4; mt++)
                af[mt] = *(const bf16_8*)(Ash + (mt*16 + ln)*72 + kk*32 + q*8);
            #pragma unroll
            for (int jn = 0; jn < 5; jn++) {
                int nt = w + jn*4;
                bfv[jn] = *(const bf16_8*)(Bsh + (nt*16 + ln)*72 + kk*32 + q*8);
            }
            #pragma unroll
            for (int mt = 0; mt < 4; mt++)
                #pragma unroll
                for (int jn = 0; jn < 5; jn++)
                    acc[mt][jn] = __builtin_amdgcn_mfma_f32_16x16x32_bf16(af[mt], bfv[jn], acc[mt][jn], 0, 0, 0);
        }
    }
    __syncthreads();

    // epilogue: h_proj columns
    #pragma unroll
    for (int mt = 0; mt < 4; mt++)
        #pragma unroll
        for (int jn = 0; jn < 4; jn++) {
            int col = (w + jn*4)*16 + ln;
            #pragma unroll
            for (int r = 0; r < 4; r++) {
                int row = mt*16 + q*4 + r;
                hproj[(size_t)(m0 + row)*256 + col] = acc[mt][jn][r];
            }
        }
    // gripper columns (ntile 16+w -> cols w*16..w*16+15 of the 64)
    {
        int cg = w*16 + ln;
        float b1 = gb1[cg];
        float w2 = gW2[cg];
        float ps[4][4];
        #pragma unroll
        for (int mt = 0; mt < 4; mt++)
            #pragma unroll
            for (int r = 0; r < 4; r++)
                ps[mt][r] = gelu_f(acc[mt][4][r] + b1) * w2;
        #pragma unroll
        for (int off = 1; off < 16; off <<= 1)
            #pragma unroll
            for (int mt = 0; mt < 4; mt++)
                #pragma unroll
                for (int r = 0; r < 4; r++)
                    ps[mt][r] += __shfl_xor(ps[mt][r], off, 64);
        if (ln == 0)
            #pragma unroll
            for (int mt = 0; mt < 4; mt++)
                #pragma unroll
                for (int r = 0; r < 4; r++)
                    gpart[mt*16 + q*4 + r][w] = ps[mt][r];
    }
    __syncthreads();
    if (tid < 64) {
        float g = gpart[tid][0] + gpart[tid][1] + gpart[tid][2] + gpart[tid][3] + gb2[0];
        grip[m0 + tid] = 1.f / (1.f + expf(-g));
    }
}

// ---------------------------------------------------------------------------
// k3: persistent 10-step MLP + SE3 integrator. grid 256 x 256; 64 rows/WG.
// ---------------------------------------------------------------------------
__launch_bounds__(256, 1)
__global__ void k3(const float* __restrict__ hproj,
                   const __bf16* __restrict__ WrT,
                   const float* __restrict__ ct,
                   const float* __restrict__ W0,
                   const float* __restrict__ Wout,
                   const float* __restrict__ bout,
                   const float* __restrict__ br,
                   const float* __restrict__ gr,
                   const float* __restrict__ ber,
                   const float* __restrict__ g0,
                   const float* __restrict__ be0,
                   const float* __restrict__ xi0,
                   const int* __restrict__ nsp,
                   float* __restrict__ out) {
    __shared__ __align__(16) __bf16 Ysh[64*264];   // 33792 B
    __shared__ __align__(16) char Ush[20480];      // union region
    __shared__ float Xsh[64][12];
    __shared__ float ctL[256];
    __shared__ __align__(16) __bf16 w0xiL[6*256];

    __bf16* Wb      = (__bf16*)Ush;                // [256][40] during matmul
    float*  xiL     = (float*)Ush;                 // [64*6]
    float*  rowred  = (float*)(Ush + 1536);        // [64*8]
    float*  vpart   = (float*)(Ush + 3584);        // [64*4*6]
    __bf16* woutT   = (__bf16*)(Ush + 9728);       // [6][256] bf16

    const int tid = threadIdx.x;
    const int w = tid >> 6;
    const int l = tid & 63;
    const int q = l >> 4;
    const int ln = l & 15;
    const int m0 = blockIdx.x * 64;
    const int ns = *nsp;
    const float dt = 1.0f / (float)ns;

    const int prow = tid >> 2;
    const int pcb  = (tid & 3) << 6;

    if (tid < 64) {
        float xi[6];
        #pragma unroll
        for (int j = 0; j < 6; j++) xi[j] = 0.1f * xi0[(size_t)(m0 + tid)*6 + j];
        float R[9], tt[3];
        exp_se3_dev(xi, R, tt);
        #pragma unroll
        for (int j = 0; j < 9; j++) Xsh[tid][j] = R[j];
        #pragma unroll
        for (int j = 0; j < 3; j++) Xsh[tid][9+j] = tt[j];
    }
    for (int i = tid; i < 1536; i += 256)
        w0xiL[i] = (__bf16)W0[(size_t)4096*256 + i];
    __syncthreads();

    for (int s = 0; s < ns; s++) {
        ctL[tid] = ct[s*256 + tid];
        if (tid < 64) {
            float R[9], p[3], xi[6];
            #pragma unroll
            for (int j = 0; j < 9; j++) R[j] = Xsh[tid][j];
            #pragma unroll
            for (int j = 0; j < 3; j++) p[j] = Xsh[tid][9+j];
            log_se3_dev(R, p, xi);
            #pragma unroll
            for (int j = 0; j < 6; j++) xiL[tid*6 + j] = xi[j];
        }
        __syncthreads();

        // ---------------- layer 0 ----------------
        float gv[64];
        {
            float xr[6];
            #pragma unroll
            for (int j = 0; j < 6; j++) xr[j] = xiL[prow*6 + j];
            const float* hp = hproj + (size_t)(m0 + prow)*256 + pcb;
            #pragma unroll
            for (int c8 = 0; c8 < 8; c8++) {
                int cb = pcb + c8*8;
                float4 h0 = *(const float4*)(hp + c8*8);
                float4 h1 = *(const float4*)(hp + c8*8 + 4);
                float4 c0 = *(const float4*)(ctL + cb);
                float4 c1 = *(const float4*)(ctL + cb + 4);
                float pr[8] = { h0.x + c0.x, h0.y + c0.y, h0.z + c0.z, h0.w + c0.w,
                                h1.x + c1.x, h1.y + c1.y, h1.z + c1.z, h1.w + c1.w };
                #pragma unroll
                for (int j = 0; j < 6; j++) {
                    bf16_8 wv = *(const bf16_8*)(w0xiL + j*256 + cb);
                    #pragma unroll
                    for (int e = 0; e < 8; e++) pr[e] += xr[j] * (float)wv[e];
                }
                #pragma unroll
                for (int e = 0; e < 8; e++) gv[c8*8 + e] = gelu_f(pr[e]);
            }
            float ps = 0.f, pq = 0.f;
            #pragma unroll
            for (int c = 0; c < 64; c++) { ps += gv[c]; pq += gv[c]*gv[c]; }
            rowred[prow*8 + (tid & 3)*2 + 0] = ps;
            rowred[prow*8 + (tid & 3)*2 + 1] = pq;
        }
        __syncthreads();
        if (tid < 64) {
            float sm = 0.f, sq = 0.f;
            #pragma unroll
            for (int k = 0; k < 4; k++) { sm += rowred[tid*8 + k*2]; sq += rowred[tid*8 + k*2 + 1]; }
            float mean = sm * (1.f/256.f);
            float var  = sq * (1.f/256.f) - mean*mean;
            rowred[tid*8 + 0] = mean;
            rowred[tid*8 + 1] = rsqrtf(var + 1e-5f);
        }
        __syncthreads();
        {
            float mean = rowred[prow*8 + 0], rstd = rowred[prow*8 + 1];
            #pragma unroll
            for (int c8 = 0; c8 < 8; c8++) {
                float4 ga = *(const float4*)(g0 + pcb + c8*8);
                float4 gb = *(const float4*)(g0 + pcb + c8*8 + 4);
                float4 ba = *(const float4*)(be0 + pcb + c8*8);
                float4 bb = *(const float4*)(be0 + pcb + c8*8 + 4);
                bf16_8 v8;
                v8[0] = (__bf16)((gv[c8*8+0] - mean)*rstd*ga.x + ba.x);
                v8[1] = (__bf16)((gv[c8*8+1] - mean)*rstd*ga.y + ba.y);
                v8[2] = (__bf16)((gv[c8*8+2] - mean)*rstd*ga.z + ba.z);
                v8[3] = (__bf16)((gv[c8*8+3] - mean)*rstd*ga.w + ba.w);
                v8[4] = (__bf16)((gv[c8*8+4] - mean)*rstd*gb.x + bb.x);
                v8[5] = (__bf16)((gv[c8*8+5] - mean)*rstd*gb.y + bb.y);
                v8[6] = (__bf16)((gv[c8*8+6] - mean)*rstd*gb.z + bb.z);
                v8[7] = (__bf16)((gv[c8*8+7] - mean)*rstd*gb.w + bb.w);
                *(bf16_8*)(Ysh + prow*264 + pcb + c8*8) = v8;
            }
        }
        // barrier provided by first slice barrier below

        // ---------------- layers 1..3 ----------------
        #pragma unroll 1
        for (int L = 0; L < 3; L++) {
            const __bf16* wsrc = WrT + (size_t)L*65536 + (size_t)tid*256;
            uint4 pf0 = *(const uint4*)(wsrc + 0);
            uint4 pf1 = *(const uint4*)(wsrc + 8);
            uint4 pf2 = *(const uint4*)(wsrc + 16);
            uint4 pf3 = *(const uint4*)(wsrc + 24);
            f32x4 acc[4][4];
            const f32x4 zv = {0.f, 0.f, 0.f, 0.f};
            #pragma unroll
            for (int a = 0; a < 4; a++)
                #pragma unroll
                for (int b = 0; b < 4; b++) acc[a][b] = zv;
            #pragma unroll 1
            for (int slice = 0; slice < 8; slice++) {
                __syncthreads();
                *(uint4*)(Wb + tid*40 + 0)  = pf0;
                *(uint4*)(Wb + tid*40 + 8)  = pf1;
                *(uint4*)(Wb + tid*40 + 16) = pf2;
                *(uint4*)(Wb + tid*40 + 24) = pf3;
                if (slice < 7) {
                    const __bf16* nx = wsrc + (slice + 1)*32;
                    pf0 = *(const uint4*)(nx + 0);
                    pf1 = *(const uint4*)(nx + 8);
                    pf2 = *(const uint4*)(nx + 16);
                    pf3 = *(const uint4*)(nx + 24);
                }
                __syncthreads();
                bf16_8 af[4], bfv[4];
                #pragma unroll
                for (int mt = 0; mt < 4; mt++)
                    af[mt] = *(const bf16_8*)(Ysh + (mt*16 + ln)*264 + slice*32 + q*8);
                #pragma unroll
                for (int nt = 0; nt < 4; nt++)
                    bfv[nt] = *(const bf16_8*)(Wb + ((w + nt*4)*16 + ln)*40 + q*8);
                #pragma unroll
                for (int mt = 0; mt < 4; mt++)
                    #pragma unroll
                    for (int nt = 0; nt < 4; nt++)
                        acc[mt][nt] = __builtin_amdgcn_mfma_f32_16x16x32_bf16(af[mt], bfv[nt], acc[mt][nt], 0, 0, 0);
            }
            __syncthreads();
            // epilogue: bias + gelu + LN, write Y
            const float* brL = br + L*256;
            const float* grL = gr + L*256;
            const float* beL = ber + L*256;
            float gelv[4][4][4];
            float ps[4][4], pq2[4][4];
            #pragma unroll
            for (int mt = 0; mt < 4; mt++)
                #pragma unroll
                for (int r = 0; r < 4; r++) { ps[mt][r] = 0.f; pq2[mt][r] = 0.f; }
            #pragma unroll
            for (int nt = 0; nt < 4; nt++) {
                int col = (w + nt*4)*16 + ln;
                float bb = brL[col];
                #pragma unroll
                for (int mt = 0; mt < 4; mt++)
                    #pragma unroll
                    for (int r = 0; r < 4; r++) {
                        float u = gelu_f(acc[mt][nt][r] + bb);
                        gelv[mt][nt][r] = u;
                        ps[mt][r] += u;
                        pq2[mt][r] += u*u;
                    }
            }
            #pragma unroll
            for (int off = 1; off < 16; off <<= 1)
                #pragma unroll
                for (int mt = 0; mt < 4; mt++)
                    #pragma unroll
                    for (int r = 0; r < 4; r++) {
                        ps[mt][r]  += __shfl_xor(ps[mt][r],  off, 64);
                        pq2[mt][r] += __shfl_xor(pq2[mt][r], off, 64);
                    }
            if (ln == 0)
                #pragma unroll
                for (int mt = 0; mt < 4; mt++)
                    #pragma unroll
                    for (int r = 0; r < 4; r++) {
                        int row = mt*16 + q*4 + r;
                        rowred[row*8 + w*2 + 0] = ps[mt][r];
                        rowred[row*8 + w*2 + 1] = pq2[mt][r];
                    }
            __syncthreads();
            if (tid < 64) {
                float sm = 0.f, sq = 0.f;
                #pragma unroll
                for (int k = 0; k < 4; k++) { sm += rowred[tid*8 + k*2]; sq += rowred[tid*8 + k*2 + 1]; }
                float mean = sm * (1.f/256.f);
                float var  = sq * (1.f/256.f) - mean*mean;
                rowred[tid*8 + 0] = mean;
                rowred[tid*8 + 1] = rsqrtf(var + 1e-5f);
            }
            __syncthreads();
            #pragma unroll
            for (int nt = 0; nt < 4; nt++) {
                int col = (w + nt*4)*16 + ln;
                float gg = grL[col], bb = beL[col];
                #pragma unroll
                for (int mt = 0; mt < 4; mt++)
                    #pragma unroll
                    for (int r = 0; r < 4; r++) {
                        int row = mt*16 + q*4 + r;
                        float mean = rowred[row*8 + 0];
                        float rstd = rowred[row*8 + 1];
                        Ysh[row*264 + col] = (__bf16)((gelv[mt][nt][r] - mean)*rstd*gg + bb);
                    }
            }
        }
        // stage Wout^T (bf16) into union region (disjoint from rowred)
        for (int i = tid; i < 1536; i += 256) {
            int j = i >> 8, k = i & 255;
            woutT[i] = (__bf16)Wout[(size_t)k*6 + j];
        }
        __syncthreads();
        // v = Y @ Wout (partials over 64-k quarters)
        {
            float p6[6] = {0.f, 0.f, 0.f, 0.f, 0.f, 0.f};
            const int kb = (tid & 3) * 64;
            #pragma unroll
            for (int kc = 0; kc < 8; kc++) {
                bf16_8 yv = *(const bf16_8*)(Ysh + prow*264 + kb + kc*8);
                float yf[8];
                #pragma unroll
                for (int e = 0; e < 8; e++) yf[e] = (float)yv[e];
                #pragma unroll
                for (int j = 0; j < 6; j++) {
                    bf16_8 wv = *(const bf16_8*)(woutT + j*256 + kb + kc*8);
                    #pragma unroll
                    for (int e = 0; e < 8; e++) p6[j] += yf[e] * (float)wv[e];
                }
            }
            #pragma unroll
            for (int j = 0; j < 6; j++) vpart[(prow*4 + (tid & 3))*6 + j] = p6[j];
        }
        __syncthreads();
        if (tid < 64) {
            float v6[6];
            #pragma unroll
            for (int j = 0; j < 6; j++) {
                float sv = vpart[(tid*4 + 0)*6 + j] + vpart[(tid*4 + 1)*6 + j]
                         + vpart[(tid*4 + 2)*6 + j] + vpart[(tid*4 + 3)*6 + j];
                v6[j] = dt * (sv + bout[j]);
            }
            float Re[9], te[3];
            exp_se3_dev(v6, Re, te);
            float R0[9], t0[3];
            #pragma unroll
            for (int j = 0; j < 9; j++) R0[j] = Xsh[tid][j];
            #pragma unroll
            for (int j = 0; j < 3; j++) t0[j] = Xsh[tid][9+j];
            float Rn[9], tn[3];
            #pragma unroll
            for (int i = 0; i < 3; i++)
                #pragma unroll
                for (int j2 = 0; j2 < 3; j2++)
                    Rn[i*3+j2] = R0[i*3+0]*Re[0*3+j2] + R0[i*3+1]*Re[1*3+j2] + R0[i*3+2]*Re[2*3+j2];
            #pragma unroll
            for (int i = 0; i < 3; i++)
                tn[i] = R0[i*3+0]*te[0] + R0[i*3+1]*te[1] + R0[i*3+2]*te[2] + t0[i];
            #pragma unroll
            for (int j = 0; j < 9; j++) Xsh[tid][j] = Rn[j];
            #pragma unroll
            for (int j = 0; j < 3; j++) Xsh[tid][9+j] = tn[j];
            if (s == ns - 1) {
                float* o = out + (size_t)(m0 + tid)*16;
                o[0]  = Rn[0]; o[1]  = Rn[1]; o[2]  = Rn[2]; o[3]  = tn[0];
                o[4]  = Rn[3]; o[5]  = Rn[4]; o[6]  = Rn[5]; o[7]  = tn[1];
                o[8]  = Rn[6]; o[9]  = Rn[7]; o[10] = Rn[8]; o[11] = tn[2];
                o[12] = 0.f; o[13] = 0.f; o[14] = 0.f; o[15] = 1.f;
            }
        }
        __syncthreads();
    }
}

extern "C" void kernel_launch(void* const* d_in, const int* in_sizes, int n_in,
                              void* d_out, int out_size, void* d_ws, size_t ws_size,
                              hipStream_t stream) {
    const float* h    = (const float*)d_in[0];
    const float* xi0  = (const float*)d_in[1];
    const float* W0   = (const float*)d_in[2];
    const float* b0   = (const float*)d_in[3];
    const float* g0   = (const float*)d_in[4];
    const float* be0  = (const float*)d_in[5];
    const float* Wr   = (const float*)d_in[6];
    const float* br   = (const float*)d_in[7];
    const float* gr   = (const float*)d_in[8];
    const float* ber  = (const float*)d_in[9];
    const float* Wout = (const float*)d_in[10];
    const float* bout = (const float*)d_in[11];
    const float* gW1  = (const float*)d_in[12];
    const float* gb1  = (const float*)d_in[13];
    const float* gW2  = (const float*)d_in[14];
    const float* gb2  = (const float*)d_in[15];
    const int*   nsp  = (const int*)d_in[16];
    float* out = (float*)d_out;

    char* ws = (char*)d_ws;
    float*  hproj = (float*)(ws + WS_HPROJ);
    __bf16* BT    = (__bf16*)(ws + WS_BT);
    __bf16* WrT   = (__bf16*)(ws + WS_WRT);
    float*  ct    = (float*)(ws + WS_CT);

    prep_pack<<<368, 256, 0, stream>>>(W0, gW1, Wr, BT, WrT);
    prep_ct<<<16, 256, 0, stream>>>(W0, b0, nsp, ct);
    k2<<<256, 256, 0, stream>>>(h, BT, gb1, gW2, gb2, hproj, out + (size_t)16384*16);
    k3<<<256, 256, 0, stream>>>(hproj, WrT, ct, W0, Wout, bout, br, gr, ber, g0, be0, xi0, nsp, out);
}